// Round 5
// baseline (609.023 us; speedup 1.0000x reference)
//
#include <hip/hip_runtime.h>
#include <hip/hip_bf16.h>

// Problem constants (GCN autoencoder)
#define N_NODES 10000
#define N_FEAT  512
#define HIDDEN  32
#define CODE    16

typedef __attribute__((ext_vector_type(8))) short  short8;
typedef __attribute__((ext_vector_type(4))) float  floatx4;

__device__ __forceinline__ float bf2f(unsigned short h) {
    return __uint_as_float(((unsigned int)h) << 16);
}
__device__ __forceinline__ unsigned short f2bf(float f) {
    unsigned int u = __float_as_uint(f);
    u += 0x7fffu + ((u >> 16) & 1u);   // RNE
    return (unsigned short)(u >> 16);
}
__device__ __forceinline__ float load_f(const void* p, size_t i, int isf32) {
    return isf32 ? ((const float*)p)[i] : bf2f(((const unsigned short*)p)[i]);
}
__device__ __forceinline__ int get_idx(const int* p, int e, int is64) {
    return is64 ? p[2 * (size_t)e] : p[e];   // LE low half holds value (<10000)
}

// ---------------------------------------------------------------------------
// K0: dtype detector (insurance; expectation: all fp32, int32 — flags 1,1,1,1,0,0).
// ---------------------------------------------------------------------------
__global__ __launch_bounds__(384) void k_detect(const unsigned short* __restrict__ t0,
                                                const unsigned short* __restrict__ t1,
                                                const unsigned short* __restrict__ t2,
                                                const unsigned short* __restrict__ t3,
                                                const int* __restrict__ i0,
                                                const int* __restrict__ i1,
                                                int* __restrict__ flags) {
    const int w    = threadIdx.x >> 6;
    const int lane = threadIdx.x & 63;
    unsigned int m = 0;
    if (w < 4) {
        const unsigned short* p = (w == 0) ? t0 : (w == 1) ? t1 : (w == 2) ? t2 : t3;
        for (int i = lane; i < 128; i += 64) {
            unsigned int v = (unsigned int)p[2 * i] & 0x7fffu;
            m = m > v ? m : v;
        }
    } else {
        const int* p = (w == 4) ? i0 : i1;
        for (int i = lane; i < 128; i += 64) {
            m |= (unsigned int)p[2 * i + 1];
        }
    }
#pragma unroll
    for (int off = 32; off > 0; off >>= 1) {
        unsigned int o = (unsigned int)__shfl_down((int)m, off, 64);
        m = (w < 4) ? (m > o ? m : o) : (m | o);
    }
    if (lane == 0) flags[w] = (w < 4) ? (m >= 0x5000u ? 1 : 0) : (m == 0u ? 1 : 0);
}

// ---------------------------------------------------------------------------
// K1: XW1 = x @ W1  [10000x512] @ [512x32] -> fp32.  (R3 fp32 fast path.)
// ---------------------------------------------------------------------------
__global__ __launch_bounds__(256) void k_xw1(const void* __restrict__ x,
                                             const void* __restrict__ W1,
                                             float* __restrict__ XW1,
                                             const int* __restrict__ flags) {
    const int xf32  = flags[0];
    const int w1f32 = flags[1];
    int t = blockIdx.x * 256 + threadIdx.x;
    if (t >= N_NODES * HIDDEN) return;
    const int n = t >> 5;
    const int c = t & 31;

    if (xf32 && w1f32) {               // expected path, wave-uniform branch
        const float* xr = (const float*)x + (size_t)n * N_FEAT;
        const float* w1 = (const float*)W1;
        float acc = 0.f;
#pragma unroll 4
        for (int k = 0; k < N_FEAT; k += 4) {
            floatx4 xa = *(const floatx4*)(xr + k);
            acc += xa[0] * w1[(k + 0) * HIDDEN + c];
            acc += xa[1] * w1[(k + 1) * HIDDEN + c];
            acc += xa[2] * w1[(k + 2) * HIDDEN + c];
            acc += xa[3] * w1[(k + 3) * HIDDEN + c];
        }
        XW1[t] = acc;
        return;
    }

    float acc = 0.f;                   // generic fallback
#pragma unroll 8
    for (int k = 0; k < N_FEAT; ++k) {
        float a = load_f(x,  (size_t)n * N_FEAT + k, xf32);
        float b = load_f(W1, (size_t)k * HIDDEN + c, w1f32);
        acc += a * b;
    }
    XW1[t] = acc;
}

// ---------------------------------------------------------------------------
// CSR build (R4): deg histogram -> block scan -> slot fill.
// Replaces 15.8M device-scope fp32 atomics with ~660K int atomics.
// ---------------------------------------------------------------------------
__global__ __launch_bounds__(256) void k_hist(const int* __restrict__ dst,
                                              int* __restrict__ deg, int E,
                                              const int* __restrict__ flags) {
    const int d64 = flags[5];
    int e = blockIdx.x * 256 + threadIdx.x;
    if (e >= E) return;
    atomicAdd(&deg[get_idx(dst, e, d64)], 1);
}

// Single block, 256 threads; 40 contiguous nodes per thread.
__global__ __launch_bounds__(256) void k_scan(const int* __restrict__ deg,
                                              int* __restrict__ rowptr, int E) {
    __shared__ int parts[256];
    const int t    = threadIdx.x;
    const int base = t * 40;
    int s = 0;
#pragma unroll 8
    for (int i = 0; i < 40; ++i) {
        int idx = base + i;
        if (idx < N_NODES) s += deg[idx];
    }
    parts[t] = s;
    __syncthreads();
    if (t == 0) {                       // serial scan of 256 partials (~256 cy)
        int run = 0;
        for (int i = 0; i < 256; ++i) { int v = parts[i]; parts[i] = run; run += v; }
    }
    __syncthreads();
    int run = parts[t];
    for (int i = 0; i < 40; ++i) {
        int idx = base + i;
        if (idx < N_NODES) { rowptr[idx] = run; run += deg[idx]; }
    }
    if (t == 255) rowptr[N_NODES] = E;
}

__global__ __launch_bounds__(256) void k_fill(const int* __restrict__ dst,
                                              const int* __restrict__ rowptr,
                                              int* __restrict__ cursor,
                                              int* __restrict__ eidx, int E,
                                              const int* __restrict__ flags) {
    const int d64 = flags[5];
    int e = blockIdx.x * 256 + threadIdx.x;
    if (e >= E) return;
    int d   = get_idx(dst, e, d64);
    int pos = rowptr[d] + atomicAdd(&cursor[d], 1);
    eidx[pos] = e;
}

// ---------------------------------------------------------------------------
// K2': pull-gather layer 1: H[node][f] = sum_e ew[e]*XW1[src[e]][f].
// 32 lanes per node; eidx/ew/src broadcast within the group; XW1 row 128B
// coalesced (XW1 1.28MB = L2/LLC-hot). No atomics, no memset.
// ---------------------------------------------------------------------------
__global__ __launch_bounds__(256) void k_gather32(const void* __restrict__ ew,
                                                  const int* __restrict__ src,
                                                  const int* __restrict__ rowptr,
                                                  const int* __restrict__ eidx,
                                                  const float* __restrict__ Xin,
                                                  float* __restrict__ H,
                                                  const int* __restrict__ flags) {
    const int ewf32 = flags[3];
    const int s64   = flags[4];
    int t = blockIdx.x * 256 + threadIdx.x;
    int node = t >> 5;
    int f    = t & 31;
    if (node >= N_NODES) return;
    int p = rowptr[node], pe = rowptr[node + 1];
    float acc = 0.f;
    for (; p < pe; ++p) {
        int   e = eidx[p];
        float w = load_f(ew, e, ewf32);
        int   s = get_idx(src, e, s64);
        acc += w * Xin[(size_t)s * HIDDEN + f];
    }
    H[(size_t)node * HIDDEN + f] = acc;
}

// ---------------------------------------------------------------------------
// K3: HW2 = relu(Hacc) @ W2   [10000x32] @ [32x16] -> fp32
// ---------------------------------------------------------------------------
__global__ __launch_bounds__(256) void k_hw2(const float* __restrict__ H,
                                             const void* __restrict__ W2,
                                             float* __restrict__ HW2,
                                             const int* __restrict__ flags) {
    const int w2f32 = flags[2];
    int t = blockIdx.x * 256 + threadIdx.x;
    if (t >= N_NODES * CODE) return;
    int n = t >> 4;
    int c = t & 15;
    float acc = 0.f;
#pragma unroll
    for (int k = 0; k < HIDDEN; ++k) {
        float h = H[n * HIDDEN + k];
        h = h > 0.f ? h : 0.f;
        acc += h * load_f(W2, k * CODE + c, w2f32);
    }
    HW2[t] = acc;
}

// ---------------------------------------------------------------------------
// K4': pull-gather layer 2 (16 lanes/node), emits bf16 zb directly (k_cvt gone).
// ---------------------------------------------------------------------------
__global__ __launch_bounds__(256) void k_gather16(const void* __restrict__ ew,
                                                  const int* __restrict__ src,
                                                  const int* __restrict__ rowptr,
                                                  const int* __restrict__ eidx,
                                                  const float* __restrict__ Hin,
                                                  unsigned short* __restrict__ zb,
                                                  const int* __restrict__ flags) {
    const int ewf32 = flags[3];
    const int s64   = flags[4];
    int t = blockIdx.x * 256 + threadIdx.x;
    int node = t >> 4;
    int f    = t & 15;
    if (node >= N_NODES) return;
    int p = rowptr[node], pe = rowptr[node + 1];
    float acc = 0.f;
    for (; p < pe; ++p) {
        int   e = eidx[p];
        float w = load_f(ew, e, ewf32);
        int   s = get_idx(src, e, s64);
        acc += w * Hin[(size_t)s * CODE + f];
    }
    zb[(size_t)node * CODE + f] = f2bf(acc);
}

// ---------------------------------------------------------------------------
// Fallback atomic-scatter kernels (used only if ws_size < CSR requirement).
// ---------------------------------------------------------------------------
__global__ __launch_bounds__(256) void k_spmm32(const void* __restrict__ ew,
                                                const int* __restrict__ src,
                                                const int* __restrict__ dst,
                                                const float* __restrict__ Xin,
                                                float* __restrict__ Hacc, int E,
                                                const int* __restrict__ flags) {
    const int ewf32 = flags[3];
    const int s64   = flags[4];
    const int d64   = flags[5];
    int t = blockIdx.x * 256 + threadIdx.x;
    int e = t >> 5;
    int f = t & 31;
    if (e >= E) return;
    float w = load_f(ew, e, ewf32);
    int   s = get_idx(src, e, s64);
    int   d = get_idx(dst, e, d64);
    float v = Xin[(size_t)s * HIDDEN + f] * w;
    atomicAdd(&Hacc[(size_t)d * HIDDEN + f], v);
}

__global__ __launch_bounds__(256) void k_spmm16(const void* __restrict__ ew,
                                                const int* __restrict__ src,
                                                const int* __restrict__ dst,
                                                const float* __restrict__ Hin,
                                                float* __restrict__ Zacc, int E,
                                                const int* __restrict__ flags) {
    const int ewf32 = flags[3];
    const int s64   = flags[4];
    const int d64   = flags[5];
    int t = blockIdx.x * 256 + threadIdx.x;
    int e = t >> 4;
    int f = t & 15;
    if (e >= E) return;
    float w = load_f(ew, e, ewf32);
    int   s = get_idx(src, e, s64);
    int   d = get_idx(dst, e, d64);
    float v = Hin[(size_t)s * CODE + f] * w;
    atomicAdd(&Zacc[(size_t)d * CODE + f], v);
}

__global__ __launch_bounds__(256) void k_cvt(const float* __restrict__ Z,
                                             unsigned short* __restrict__ zb) {
    int t = blockIdx.x * 256 + threadIdx.x;
    if (t >= N_NODES * CODE) return;
    zb[t] = f2bf(Z[t]);
}

// ---------------------------------------------------------------------------
// K6: out = sigmoid(zb @ zb^T)  (R3 LDS-staged full-line drain, unchanged)
// ---------------------------------------------------------------------------
#define TLD 68   // LDS row stride in floats (64 data + 4 pad; 272B = 17*16B)

__global__ __launch_bounds__(256) void k_dec(const unsigned short* __restrict__ zb,
                                             float* __restrict__ out) {
    __shared__ float tile[64 * TLD];   // 17.4 KB

    const int wave = threadIdx.x >> 6;
    const int lane = threadIdx.x & 63;
    const int l16  = lane & 15;
    const int quad = lane >> 4;

    const int rblk = blockIdx.y * 64;
    const int cblk = blockIdx.x * 64;
    const int r0   = rblk + wave * 16;

    const short8 zero8 = {0, 0, 0, 0, 0, 0, 0, 0};

    int ra = r0 + l16;
    if (ra > N_NODES - 1) ra = N_NODES - 1;
    short8 afr = zero8;
    if (quad < 2) afr = *(const short8*)(zb + (size_t)ra * CODE + quad * 8);

#pragma unroll
    for (int t = 0; t < 4; ++t) {
        int cb = cblk + t * 16 + l16;
        if (cb > N_NODES - 1) cb = N_NODES - 1;
        short8 bfr = zero8;
        if (quad < 2) bfr = *(const short8*)(zb + (size_t)cb * CODE + quad * 8);
        floatx4 z4 = {0.f, 0.f, 0.f, 0.f};
        floatx4 acc = __builtin_amdgcn_mfma_f32_16x16x32_bf16(afr, bfr, z4, 0, 0, 0);
        const int lrow = wave * 16 + quad * 4;
        const int lcol = t * 16 + l16;
#pragma unroll
        for (int r = 0; r < 4; ++r) {
            tile[(lrow + r) * TLD + lcol] = acc[r];
        }
    }
    __syncthreads();

    const int drow = threadIdx.x >> 4;          // 0..15
    const int dcol = (threadIdx.x & 15) * 4;    // 0,4,..,60
#pragma unroll
    for (int p = 0; p < 4; ++p) {
        const int lr = p * 16 + drow;
        floatx4 v;
#pragma unroll
        for (int j = 0; j < 4; ++j) {
            float s = tile[lr * TLD + dcol + j];
            float e = __builtin_amdgcn_exp2f(-1.442695041f * s);
            v[j] = __builtin_amdgcn_rcpf(1.f + e);
        }
        const int grow = rblk + lr;
        const int gcol = cblk + dcol;
        if (grow < N_NODES && gcol < N_NODES) {   // N%4==0: float4-exact guard
            __builtin_nontemporal_store(v, (floatx4*)(out + (size_t)grow * N_NODES + gcol));
        }
    }
}

// ---------------------------------------------------------------------------
// Workspace map (int offsets into ws):
//  floats: XW1 [0,320000) | Hacc [320000,640000) | HW2 [0,160000) over dead XW1
//          Zacc [160000,320000) (fallback only) | zb ushort @ float ofs 320000
//  ints:   flags @640000(6) | deg @640008(10000) | cursor @650008(10000)
//          rowptr @660008(10001) | eidx @670016(E)
// CSR path needs (670016+E)*4 bytes of workspace.
// ---------------------------------------------------------------------------
extern "C" void kernel_launch(void* const* d_in, const int* in_sizes, int n_in,
                              void* d_out, int out_size, void* d_ws, size_t ws_size,
                              hipStream_t stream) {
    const void* x  = d_in[0];
    const void* W1 = d_in[1];
    const void* W2 = d_in[2];
    const void* ew = d_in[3];
    const int* src = (const int*)d_in[4];
    const int* dst = (const int*)d_in[5];
    float* out = (float*)d_out;
    const int E = in_sizes[3];   // 330000 edges

    float* ws   = (float*)d_ws;
    int*   wsi  = (int*)d_ws;
    float* XW1  = ws;
    float* Hacc = ws + 320000;
    float* HW2  = ws;
    float* Zacc = ws + 160000;
    unsigned short* zb = (unsigned short*)(ws + 320000);
    int* flags  = wsi + 640000;
    int* deg    = wsi + 640008;
    int* cursor = wsi + 650008;
    int* rowptr = wsi + 660008;
    int* eidx   = wsi + 670016;

    const size_t need_csr = (size_t)(670016 + E) * 4;
    const int use_csr = (ws_size >= need_csr);

    k_detect<<<1, 384, 0, stream>>>((const unsigned short*)x,
                                    (const unsigned short*)W1,
                                    (const unsigned short*)W2,
                                    (const unsigned short*)ew,
                                    src, dst, flags);

    if (use_csr) {
        // zero deg+cursor (contiguous 20000 ints)
        hipMemsetAsync(deg, 0, 20000 * sizeof(int), stream);
        k_hist<<<(E + 255) / 256, 256, 0, stream>>>(dst, deg, E, flags);
        k_scan<<<1, 256, 0, stream>>>(deg, rowptr, E);
        k_fill<<<(E + 255) / 256, 256, 0, stream>>>(dst, rowptr, cursor, eidx, E, flags);

        k_xw1<<<(N_NODES * HIDDEN + 255) / 256, 256, 0, stream>>>(x, W1, XW1, flags);
        k_gather32<<<(N_NODES * 32 + 255) / 256, 256, 0, stream>>>(ew, src, rowptr, eidx,
                                                                   XW1, Hacc, flags);
        k_hw2<<<(N_NODES * CODE + 255) / 256, 256, 0, stream>>>(Hacc, W2, HW2, flags);
        k_gather16<<<(N_NODES * 16 + 255) / 256, 256, 0, stream>>>(ew, src, rowptr, eidx,
                                                                   HW2, zb, flags);
    } else {
        // fallback: proven atomic-scatter path
        hipMemsetAsync(Hacc, 0, 320000 * sizeof(float), stream);
        k_xw1<<<(N_NODES * HIDDEN + 255) / 256, 256, 0, stream>>>(x, W1, XW1, flags);
        k_spmm32<<<(E * 32 + 255) / 256, 256, 0, stream>>>(ew, src, dst, XW1, Hacc, E, flags);
        hipMemsetAsync(Zacc, 0, 160000 * sizeof(float), stream);
        k_hw2<<<(N_NODES * CODE + 255) / 256, 256, 0, stream>>>(Hacc, W2, HW2, flags);
        k_spmm16<<<(E * 16 + 255) / 256, 256, 0, stream>>>(ew, src, dst, HW2, Zacc, E, flags);
        k_cvt<<<(N_NODES * CODE + 255) / 256, 256, 0, stream>>>(Zacc, zb);
    }

    dim3 grid((N_NODES + 63) / 64, (N_NODES + 63) / 64);
    k_dec<<<grid, 256, 0, stream>>>(zb, out);
}

// Round 6
// 544.592 us; speedup vs baseline: 1.1183x; 1.1183x over previous
//
#include <hip/hip_runtime.h>
#include <hip/hip_bf16.h>

// Problem constants (GCN autoencoder)
#define N_NODES 10000
#define N_FEAT  512
#define HIDDEN  32
#define CODE    16

typedef __attribute__((ext_vector_type(8))) short  short8;
typedef __attribute__((ext_vector_type(4))) float  floatx4;

__device__ __forceinline__ float bf2f(unsigned short h) {
    return __uint_as_float(((unsigned int)h) << 16);
}
__device__ __forceinline__ unsigned short f2bf(float f) {
    unsigned int u = __float_as_uint(f);
    u += 0x7fffu + ((u >> 16) & 1u);   // RNE
    return (unsigned short)(u >> 16);
}
__device__ __forceinline__ float load_f(const void* p, size_t i, int isf32) {
    return isf32 ? ((const float*)p)[i] : bf2f(((const unsigned short*)p)[i]);
}
__device__ __forceinline__ int get_idx(const int* p, int e, int is64) {
    return is64 ? p[2 * (size_t)e] : p[e];   // LE low half holds value (<10000)
}

// ---------------------------------------------------------------------------
// K0: dtype detector (insurance; expectation: all fp32, int32 — flags 1,1,1,1,0,0).
// ---------------------------------------------------------------------------
__global__ __launch_bounds__(384) void k_detect(const unsigned short* __restrict__ t0,
                                                const unsigned short* __restrict__ t1,
                                                const unsigned short* __restrict__ t2,
                                                const unsigned short* __restrict__ t3,
                                                const int* __restrict__ i0,
                                                const int* __restrict__ i1,
                                                int* __restrict__ flags) {
    const int w    = threadIdx.x >> 6;
    const int lane = threadIdx.x & 63;
    unsigned int m = 0;
    if (w < 4) {
        const unsigned short* p = (w == 0) ? t0 : (w == 1) ? t1 : (w == 2) ? t2 : t3;
        for (int i = lane; i < 128; i += 64) {
            unsigned int v = (unsigned int)p[2 * i] & 0x7fffu;
            m = m > v ? m : v;
        }
    } else {
        const int* p = (w == 4) ? i0 : i1;
        for (int i = lane; i < 128; i += 64) {
            m |= (unsigned int)p[2 * i + 1];
        }
    }
#pragma unroll
    for (int off = 32; off > 0; off >>= 1) {
        unsigned int o = (unsigned int)__shfl_down((int)m, off, 64);
        m = (w < 4) ? (m > o ? m : o) : (m | o);
    }
    if (lane == 0) flags[w] = (w < 4) ? (m >= 0x5000u ? 1 : 0) : (m == 0u ? 1 : 0);
}

// ---------------------------------------------------------------------------
// K1: XW1 = x @ W1 (R3 fp32 fast path) + zeroes Hacc and Zacc (R6: folds the
// two hipMemsetAsync dispatches into this kernel's exactly-320000 threads).
// Requires Zacc disjoint from XW1 (layout A).
// ---------------------------------------------------------------------------
__global__ __launch_bounds__(256) void k_xw1(const void* __restrict__ x,
                                             const void* __restrict__ W1,
                                             float* __restrict__ XW1,
                                             float* __restrict__ Hacc,
                                             float* __restrict__ Zacc,
                                             int zero_acc,
                                             const int* __restrict__ flags) {
    const int xf32  = flags[0];
    const int w1f32 = flags[1];
    int t = blockIdx.x * 256 + threadIdx.x;
    if (t >= N_NODES * HIDDEN) return;
    if (zero_acc) {
        Hacc[t] = 0.f;                         // 320000 = N_NODES*HIDDEN exact
        if (t < N_NODES * CODE) Zacc[t] = 0.f; // first 160000 threads
    }
    const int n = t >> 5;
    const int c = t & 31;

    if (xf32 && w1f32) {               // expected path, wave-uniform branch
        const float* xr = (const float*)x + (size_t)n * N_FEAT;
        const float* w1 = (const float*)W1;
        float acc = 0.f;
#pragma unroll 4
        for (int k = 0; k < N_FEAT; k += 4) {
            floatx4 xa = *(const floatx4*)(xr + k);
            acc += xa[0] * w1[(k + 0) * HIDDEN + c];
            acc += xa[1] * w1[(k + 1) * HIDDEN + c];
            acc += xa[2] * w1[(k + 2) * HIDDEN + c];
            acc += xa[3] * w1[(k + 3) * HIDDEN + c];
        }
        XW1[t] = acc;
        return;
    }

    float acc = 0.f;                   // generic fallback
#pragma unroll 8
    for (int k = 0; k < N_FEAT; ++k) {
        float a = load_f(x,  (size_t)n * N_FEAT + k, xf32);
        float b = load_f(W1, (size_t)k * HIDDEN + c, w1f32);
        acc += a * b;
    }
    XW1[t] = acc;
}

// ---------------------------------------------------------------------------
// K2: Hacc[dst] += ew * XW1[src]   (32 feats/edge, fp32 atomics — proven R4)
// ---------------------------------------------------------------------------
__global__ __launch_bounds__(256) void k_spmm32(const void* __restrict__ ew,
                                                const int* __restrict__ src,
                                                const int* __restrict__ dst,
                                                const float* __restrict__ Xin,
                                                float* __restrict__ Hacc, int E,
                                                const int* __restrict__ flags) {
    const int ewf32 = flags[3];
    const int s64   = flags[4];
    const int d64   = flags[5];
    int t = blockIdx.x * 256 + threadIdx.x;
    int e = t >> 5;
    int f = t & 31;
    if (e >= E) return;
    float w = load_f(ew, e, ewf32);
    int   s = get_idx(src, e, s64);
    int   d = get_idx(dst, e, d64);
    float v = Xin[(size_t)s * HIDDEN + f] * w;
    atomicAdd(&Hacc[(size_t)d * HIDDEN + f], v);
}

// ---------------------------------------------------------------------------
// K4 (R6, fused): Zacc[dst][f] += ew * (relu(Hacc[src]) · W2[:,f]).
// Recomputes the 32-FLOP relu-dot per edge instead of materializing HW2
// (169 MFLOP total — trivial; H row 128B broadcast L2-hot, W2 L1-hot).
// Deletes the k_hw2 dispatch and the HW2 1.3MB round-trip.
// ---------------------------------------------------------------------------
__global__ __launch_bounds__(256) void k_spmm16f(const void* __restrict__ ew,
                                                 const int* __restrict__ src,
                                                 const int* __restrict__ dst,
                                                 const float* __restrict__ Hacc,
                                                 const void* __restrict__ W2,
                                                 float* __restrict__ Zacc, int E,
                                                 const int* __restrict__ flags) {
    const int w2f32 = flags[2];
    const int ewf32 = flags[3];
    const int s64   = flags[4];
    const int d64   = flags[5];
    int t = blockIdx.x * 256 + threadIdx.x;
    int e = t >> 4;
    int f = t & 15;
    if (e >= E) return;
    float w = load_f(ew, e, ewf32);
    int   s = get_idx(src, e, s64);
    int   d = get_idx(dst, e, d64);
    const float* hr = Hacc + (size_t)s * HIDDEN;
    float acc = 0.f;
#pragma unroll
    for (int k = 0; k < HIDDEN; ++k) {
        float h = hr[k];
        h = h > 0.f ? h : 0.f;
        acc += h * load_f(W2, k * CODE + f, w2f32);
    }
    atomicAdd(&Zacc[(size_t)d * CODE + f], w * acc);
}

// ---------------------------------------------------------------------------
// K6: out = sigmoid(Z @ Z^T), fp32 Z input (R6: k_cvt deleted; f2bf done
// in-register, identical RNE rounding on A and B frags -> symmetry intact;
// the ~120 extra VALU ops/thread hide under the NT-store-bound wait).
// R3 LDS-staged full-line drain retained.
// ---------------------------------------------------------------------------
#define TLD 68   // LDS row stride in floats (64 data + 4 pad; 272B = 17*16B)

__device__ __forceinline__ short8 cvt_frag(const float* __restrict__ Z, int row, int quad) {
    short8 r = {0, 0, 0, 0, 0, 0, 0, 0};
    if (quad < 2) {
        floatx4 a = *(const floatx4*)(Z + (size_t)row * CODE + quad * 8);
        floatx4 b = *(const floatx4*)(Z + (size_t)row * CODE + quad * 8 + 4);
        r[0] = (short)f2bf(a[0]); r[1] = (short)f2bf(a[1]);
        r[2] = (short)f2bf(a[2]); r[3] = (short)f2bf(a[3]);
        r[4] = (short)f2bf(b[0]); r[5] = (short)f2bf(b[1]);
        r[6] = (short)f2bf(b[2]); r[7] = (short)f2bf(b[3]);
    }
    return r;
}

__global__ __launch_bounds__(256) void k_dec(const float* __restrict__ Z,
                                             float* __restrict__ out) {
    __shared__ float tile[64 * TLD];   // 17.4 KB

    const int wave = threadIdx.x >> 6;
    const int lane = threadIdx.x & 63;
    const int l16  = lane & 15;
    const int quad = lane >> 4;

    const int rblk = blockIdx.y * 64;
    const int cblk = blockIdx.x * 64;
    const int r0   = rblk + wave * 16;

    int ra = r0 + l16;
    if (ra > N_NODES - 1) ra = N_NODES - 1;
    short8 afr = cvt_frag(Z, ra, quad);

#pragma unroll
    for (int t = 0; t < 4; ++t) {
        int cb = cblk + t * 16 + l16;
        if (cb > N_NODES - 1) cb = N_NODES - 1;
        short8 bfr = cvt_frag(Z, cb, quad);
        floatx4 z4 = {0.f, 0.f, 0.f, 0.f};
        floatx4 acc = __builtin_amdgcn_mfma_f32_16x16x32_bf16(afr, bfr, z4, 0, 0, 0);
        const int lrow = wave * 16 + quad * 4;
        const int lcol = t * 16 + l16;
#pragma unroll
        for (int r = 0; r < 4; ++r) {
            tile[(lrow + r) * TLD + lcol] = acc[r];
        }
    }
    __syncthreads();

    const int drow = threadIdx.x >> 4;          // 0..15
    const int dcol = (threadIdx.x & 15) * 4;    // 0,4,..,60
#pragma unroll
    for (int p = 0; p < 4; ++p) {
        const int lr = p * 16 + drow;
        floatx4 v;
#pragma unroll
        for (int j = 0; j < 4; ++j) {
            float s = tile[lr * TLD + dcol + j];
            float e = __builtin_amdgcn_exp2f(-1.442695041f * s);
            v[j] = __builtin_amdgcn_rcpf(1.f + e);
        }
        const int grow = rblk + lr;
        const int gcol = cblk + dcol;
        if (grow < N_NODES && gcol < N_NODES) {   // N%4==0: float4-exact guard
            __builtin_nontemporal_store(v, (floatx4*)(out + (size_t)grow * N_NODES + gcol));
        }
    }
}

// ---------------------------------------------------------------------------
// Workspace layouts:
//  A (ws >= 3.21 MB, expected — R5 proved >= 4.0 MB):
//    XW1 [0,320000) | Hacc [320000,640000) | Zacc [640000,800000) | flags @800000
//    5 dispatches: detect, xw1(+zeroH,Z), spmm32, spmm16f, dec.
//  B (fallback, ws >= 2.56 MB): R4-style with memset zeroing:
//    XW1 [0,320000) | Hacc [320000,640000) | Zacc [160000,320000) over dead XW1
//    flags @640000.  7 dispatches (2 memsets, no in-kernel zeroing).
// ---------------------------------------------------------------------------
extern "C" void kernel_launch(void* const* d_in, const int* in_sizes, int n_in,
                              void* d_out, int out_size, void* d_ws, size_t ws_size,
                              hipStream_t stream) {
    const void* x  = d_in[0];
    const void* W1 = d_in[1];
    const void* W2 = d_in[2];
    const void* ew = d_in[3];
    const int* src = (const int*)d_in[4];
    const int* dst = (const int*)d_in[5];
    float* out = (float*)d_out;
    const int E = in_sizes[3];   // 330000 edges

    float* ws   = (float*)d_ws;
    float* XW1  = ws;
    float* Hacc = ws + 320000;

    const size_t need_a = (size_t)(800006) * 4;
    const int layout_a = (ws_size >= need_a);

    float* Zacc = layout_a ? (ws + 640000) : (ws + 160000);
    int*   flags = (int*)d_ws + (layout_a ? 800000 : 640000);

    k_detect<<<1, 384, 0, stream>>>((const unsigned short*)x,
                                    (const unsigned short*)W1,
                                    (const unsigned short*)W2,
                                    (const unsigned short*)ew,
                                    src, dst, flags);

    if (!layout_a) {
        hipMemsetAsync(Hacc, 0, 320000 * sizeof(float), stream);
        hipMemsetAsync(Zacc, 0, 160000 * sizeof(float), stream);
    }

    k_xw1<<<(N_NODES * HIDDEN + 255) / 256, 256, 0, stream>>>(
        x, W1, XW1, Hacc, Zacc, layout_a ? 1 : 0, flags);
    k_spmm32<<<(E * 32 + 255) / 256, 256, 0, stream>>>(ew, src, dst, XW1, Hacc, E, flags);
    k_spmm16f<<<(E * 16 + 255) / 256, 256, 0, stream>>>(ew, src, dst, Hacc, W2, Zacc, E, flags);

    dim3 grid((N_NODES + 63) / 64, (N_NODES + 63) / 64);
    k_dec<<<grid, 256, 0, stream>>>(Zacc, out);
}